// Round 12
// baseline (287.779 us; speedup 1.0000x reference)
//
#include <hip/hip_runtime.h>

#define NN 10000
#define EE 160000
#define DD 1024          // D_IN + H
#define FOURH 2048
#define HH 512
#define MT 20000         // B*N
#define MPAD 20224       // 158 * 128

typedef __attribute__((ext_vector_type(8))) short bf16x8;
typedef __attribute__((ext_vector_type(4))) float f32x4;

typedef __attribute__((address_space(1))) void gvoid;
typedef __attribute__((address_space(3))) void lvoid;

__device__ inline void gload16(const void* g, void* l) {
    __builtin_amdgcn_global_load_lds((gvoid*)g, (lvoid*)l, 16, 0, 0);
}

__device__ inline unsigned short f2bf(float f) {
    unsigned u = __float_as_uint(f);
    u += 0x7fff + ((u >> 16) & 1);   // RNE
    return (unsigned short)(u >> 16);
}

__device__ inline float bflo(unsigned u) { return __uint_as_float(u << 16); }
__device__ inline float bfhi(unsigned u) { return __uint_as_float(u & 0xffff0000u); }

__device__ inline float sigmoidf_(float x) {
    x = fminf(fmaxf(x, -30.f), 30.f);
    return 1.f / (1.f + __expf(-x));
}
__device__ inline float tanhf_(float x) {
    x = fminf(fmaxf(x, -15.f), 15.f);
    float e = __expf(2.f * x);
    return (e - 1.f) / (e + 1.f);
}

// ---------------- CSR build ----------------

// 1-block hierarchical scan: wave shfl-scan + 16-partial scan (3 barriers/chunk)
__global__ __launch_bounds__(1024) void scan_kernel(
    const int* __restrict__ counts, int* __restrict__ offsets,
    int* __restrict__ cursor, float* __restrict__ dinv,
    float* __restrict__ invdeg)
{
    __shared__ int wsum[16];
    int tid = threadIdx.x;
    int lane = tid & 63, wv = tid >> 6;
    if (tid == 0) offsets[0] = 0;
    int running = 0;
    for (int base = 0; base < NN; base += 1024) {
        int i = base + tid;
        int v = (i < NN) ? counts[i] : 0;
        int x = v;
#pragma unroll
        for (int d = 1; d < 64; d <<= 1) {
            int t = __shfl_up(x, d, 64);
            if (lane >= d) x += t;
        }
        if (lane == 63) wsum[wv] = x;
        __syncthreads();
        if (wv == 0) {
            int ws = (lane < 16) ? wsum[lane] : 0;
#pragma unroll
            for (int d = 1; d < 16; d <<= 1) {
                int t = __shfl_up(ws, d, 64);
                if (lane >= d) ws += t;
            }
            if (lane < 16) wsum[lane] = ws;
        }
        __syncthreads();
        int wbase = (wv == 0) ? 0 : wsum[wv - 1];
        int incl = x + wbase + running;
        if (i < NN) {
            offsets[i + 1] = incl;
            cursor[i] = incl - v;            // exclusive
            float deg = (float)(v + 1);
            dinv[i] = rsqrtf(deg);
            invdeg[i] = 1.0f / deg;
        }
        running += wsum[15];
        __syncthreads();
    }
}

__global__ void fill_kernel(const int* __restrict__ src, const int* __restrict__ dst,
                            int* __restrict__ cursor, const float* __restrict__ dinv,
                            int* __restrict__ csr_src, float* __restrict__ csr_w) {
    int e = blockIdx.x * blockDim.x + threadIdx.x;
    if (e < EE) {
        int s = src[e], d = dst[e];
        int p = atomicAdd(&cursor[d], 1);
        csr_src[p] = s;
        csr_w[p] = dinv[s] * dinv[d];
    }
}

// ---------------- fused prep: convert + W-transpose + agg-pad-zero + count ---
// blocks [0,NN): x,h -> packed bf16 rows xhc[n][2048]
// blocks [NN,NN+2048): W[k][j] -> bf16 Wt[j][k]
// blocks [NN+2048,NN+2048+224): zero agg pad rows
// blocks [NN+2048+224, +625): degree count (atomics; overlaps streaming work)

__global__ __launch_bounds__(256) void prep_kernel(
    const float* __restrict__ x, const float* __restrict__ h,
    const float* __restrict__ W, const int* __restrict__ dst,
    unsigned short* __restrict__ xhc, unsigned short* __restrict__ Wt,
    unsigned short* __restrict__ agg, int* __restrict__ counts)
{
    __shared__ float tile[32][33];
    int b = blockIdx.x;
    int t = threadIdx.x;
    if (b < NN) {
        int n = b;
        int sec = t >> 6;        // 0..3
        int li = t & 63;         // 8 floats each
        const float* srcp;
        if (sec == 0)      srcp = x + (size_t)n * 512 + li * 8;
        else if (sec == 1) srcp = h + (size_t)n * 512 + li * 8;
        else if (sec == 2) srcp = x + (size_t)(NN + n) * 512 + li * 8;
        else               srcp = h + (size_t)(NN + n) * 512 + li * 8;
        float4 v0 = *(const float4*)srcp;
        float4 v1 = *(const float4*)(srcp + 4);
        uint4 o;
        o.x = f2bf(v0.x) | ((unsigned)f2bf(v0.y) << 16);
        o.y = f2bf(v0.z) | ((unsigned)f2bf(v0.w) << 16);
        o.z = f2bf(v1.x) | ((unsigned)f2bf(v1.y) << 16);
        o.w = f2bf(v1.z) | ((unsigned)f2bf(v1.w) << 16);
        *(uint4*)(xhc + (size_t)n * 2048 + t * 8) = o;
    } else if (b < NN + 2048) {
        int idx = b - NN;
        int k0 = (idx & 31) * 32;
        int j0 = (idx >> 5) * 32;
        int tx = t & 31;
        int ty = t >> 5;         // 0..7
#pragma unroll
        for (int i = 0; i < 32; i += 8)
            tile[ty + i][tx] = W[(size_t)(k0 + ty + i) * FOURH + (j0 + tx)];
        __syncthreads();
#pragma unroll
        for (int i = 0; i < 32; i += 8)
            Wt[(size_t)(j0 + ty + i) * DD + (k0 + tx)] = f2bf(tile[tx][ty + i]);
    } else if (b < NN + 2048 + 224) {
        int idx = (b - NN - 2048) * 256 + t;       // 224*256 = 57344 ushort4
        ushort4* p = (ushort4*)(agg + (size_t)MT * DD);
        p[idx] = make_ushort4(0, 0, 0, 0);
    } else {
        int e = (b - NN - 2048 - 224) * 256 + t;   // 625*256 = 160000
        if (e < EE) atomicAdd(&counts[dst[e]], 1);
    }
}

// ---------------- aggregation (bf16 gather, fp32 accumulate, 4-edge MLP) -----

__global__ __launch_bounds__(256) void agg_kernel(
    const unsigned short* __restrict__ xhc,
    const int* __restrict__ csr_src, const float* __restrict__ csr_w,
    const int* __restrict__ offsets, const float* __restrict__ invdeg,
    unsigned short* __restrict__ agg)
{
    int n = blockIdx.x;
    int t = threadIdx.x;                 // 8 bf16 per thread of the 2048-wide row
    const unsigned short* base = xhc + t * 8;
    float a0 = 0, a1 = 0, a2 = 0, a3 = 0, a4 = 0, a5 = 0, a6 = 0, a7 = 0;
    int beg = offsets[n], end = offsets[n + 1];
    int e = beg;
    for (; e + 4 <= end; e += 4) {
        int s0 = csr_src[e], s1 = csr_src[e + 1], s2 = csr_src[e + 2], s3 = csr_src[e + 3];
        float w0 = csr_w[e], w1 = csr_w[e + 1], w2 = csr_w[e + 2], w3 = csr_w[e + 3];
        uint4 v0 = *(const uint4*)(base + (size_t)s0 * 2048);
        uint4 v1 = *(const uint4*)(base + (size_t)s1 * 2048);
        uint4 v2 = *(const uint4*)(base + (size_t)s2 * 2048);
        uint4 v3 = *(const uint4*)(base + (size_t)s3 * 2048);
        a0 += w0 * bflo(v0.x); a1 += w0 * bfhi(v0.x);
        a2 += w0 * bflo(v0.y); a3 += w0 * bfhi(v0.y);
        a4 += w0 * bflo(v0.z); a5 += w0 * bfhi(v0.z);
        a6 += w0 * bflo(v0.w); a7 += w0 * bfhi(v0.w);
        a0 += w1 * bflo(v1.x); a1 += w1 * bfhi(v1.x);
        a2 += w1 * bflo(v1.y); a3 += w1 * bfhi(v1.y);
        a4 += w1 * bflo(v1.z); a5 += w1 * bfhi(v1.z);
        a6 += w1 * bflo(v1.w); a7 += w1 * bfhi(v1.w);
        a0 += w2 * bflo(v2.x); a1 += w2 * bfhi(v2.x);
        a2 += w2 * bflo(v2.y); a3 += w2 * bfhi(v2.y);
        a4 += w2 * bflo(v2.z); a5 += w2 * bfhi(v2.z);
        a6 += w2 * bflo(v2.w); a7 += w2 * bfhi(v2.w);
        a0 += w3 * bflo(v3.x); a1 += w3 * bfhi(v3.x);
        a2 += w3 * bflo(v3.y); a3 += w3 * bfhi(v3.y);
        a4 += w3 * bflo(v3.z); a5 += w3 * bfhi(v3.z);
        a6 += w3 * bflo(v3.w); a7 += w3 * bfhi(v3.w);
    }
    for (; e < end; ++e) {
        int s = csr_src[e];
        float w = csr_w[e];
        uint4 v = *(const uint4*)(base + (size_t)s * 2048);
        a0 += w * bflo(v.x); a1 += w * bfhi(v.x);
        a2 += w * bflo(v.y); a3 += w * bfhi(v.y);
        a4 += w * bflo(v.z); a5 += w * bfhi(v.z);
        a6 += w * bflo(v.w); a7 += w * bfhi(v.w);
    }
    float sw = invdeg[n];
    {
        uint4 v = *(const uint4*)(base + (size_t)n * 2048);
        a0 += sw * bflo(v.x); a1 += sw * bfhi(v.x);
        a2 += sw * bflo(v.y); a3 += sw * bfhi(v.y);
        a4 += sw * bflo(v.z); a5 += sw * bfhi(v.z);
        a6 += sw * bflo(v.w); a7 += sw * bfhi(v.w);
    }
    uint4 o;
    o.x = f2bf(a0) | ((unsigned)f2bf(a1) << 16);
    o.y = f2bf(a2) | ((unsigned)f2bf(a3) << 16);
    o.z = f2bf(a4) | ((unsigned)f2bf(a5) << 16);
    o.w = f2bf(a6) | ((unsigned)f2bf(a7) << 16);
    int bsel = t >> 7;                   // batch
    int d = (t & 127) * 8;               // dim within 1024
    *(uint4*)(agg + ((size_t)(bsel * NN + n)) * DD + d) = o;
}

// ---------------- GEMM + fused LSTM epilogue ----------------
// r8 geometry at 5 blocks/CU (clean test; r9's 5-block run was polluted by agg
// slicing): 128x128 tile (cols interleaved: gate=c&3, h=h0+(c>>2)), BK=64,
// 256 thr = 4 waves (2M x 2N), per-wave 64x64, acc[4][4], single-buffered 32KB
// LDS -> 5 blocks/CU (160KB exactly). 2-barrier compiler-scheduled loop.
// Swizzle = r6-measured conflict-free: 128B rows, phys 16B slot s of row r holds
// k-chunk s^(r&7) (pre-swizzled global source, linear LDS dest); frag slot
// ((lane>>4)^(lane&7)), k-half via ^64. Grid 2528 = 8 XCD chunks x 316,
// h-tile-fastest (16 blocks share one A-panel). Merged h+c epilogue (2 barriers).

__global__ __launch_bounds__(256, 5) void gemm_lstm_kernel(
    const unsigned short* __restrict__ agg,
    const unsigned short* __restrict__ Wt,
    const float* __restrict__ bias,
    const float* __restrict__ c_cur,
    float* __restrict__ out)
{
    __shared__ char smem[32768];        // A [128][128B] at 0, B [128][128B] at 16384

    const int tid = threadIdx.x;
    const int lane = tid & 63;
    const int wave = tid >> 6;          // 0..3
    const int waveM = wave >> 1;        // 0..1 (64 rows each)
    const int waveN = wave & 1;         // 0..1 (64 interleaved cols = 16 h each)

    const int orig = blockIdx.x;        // 2528 = 8 * 316
    const int f = (orig & 7) * 316 + (orig >> 3);
    const int blockM = f >> 4;          // 0..157
    const int h0 = (f & 15) * 32;
    const int m0 = blockM * 128;

    // fragment read offsets (kh=0); kh=1 via ^64 (slot s holds chunk s^(r&7))
    const int slot = ((lane >> 4) ^ (lane & 7)) * 16;
    const int aOff = (waveM * 64 + (lane & 15)) * 128 + slot;
    const int bOff = 16384 + (waveN * 64 + (lane & 15)) * 128 + slot;

    // staging: chunk q = l*256+tid -> row/col l*32+(tid>>3), slot tid&7,
    // global k-chunk (tid&7)^((tid>>3)&7)   [l*32 drops out of &7]
    const int koff = 8 * ((tid & 7) ^ ((tid >> 3) & 7));
    const unsigned short* aSrc = agg + (size_t)(m0 + (tid >> 3)) * DD + koff;
    const unsigned short* bSrc = Wt + (size_t)(((tid >> 3) & 3) * 512 + h0 + (tid >> 5)) * DD + koff;

    f32x4 acc[4][4];
#pragma unroll
    for (int i = 0; i < 4; ++i)
#pragma unroll
        for (int j = 0; j < 4; ++j) {
            f32x4 z = {0.f, 0.f, 0.f, 0.f};
            acc[i][j] = z;
        }

    for (int kt = 0; kt < 16; ++kt) {
        __syncthreads();
#pragma unroll
        for (int l = 0; l < 4; ++l)
            gload16(aSrc + (size_t)l * 32 * DD + kt * 64, smem + l * 4096 + tid * 16);
#pragma unroll
        for (int l = 0; l < 4; ++l)
            gload16(bSrc + (size_t)l * 8 * DD + kt * 64, smem + 16384 + l * 4096 + tid * 16);
        __syncthreads();
#pragma unroll
        for (int ksub = 0; ksub < 2; ++ksub) {
            const int kx = ksub * 64;
            bf16x8 aF[4], bF[4];
#pragma unroll
            for (int mi = 0; mi < 4; ++mi)
                aF[mi] = *(const bf16x8*)(smem + (aOff ^ kx) + mi * 2048);
#pragma unroll
            for (int ci = 0; ci < 4; ++ci)
                bF[ci] = *(const bf16x8*)(smem + (bOff ^ kx) + ci * 2048);
#pragma unroll
            for (int ci = 0; ci < 4; ++ci)
#pragma unroll
                for (int mi = 0; mi < 4; ++mi)
                    acc[mi][ci] = __builtin_amdgcn_mfma_f32_16x16x32_bf16(aF[mi], bF[ci], acc[mi][ci], 0, 0, 0);
        }
    }

    // ---- epilogue: quad transpose -> LSTM math -> LDS-staged coalesced stores ----
    __syncthreads();                     // all LDS reads done; reuse smem
    float* fbh = (float*)smem;           // [128][32] f32 (16KB), h-XOR ((row&7)<<2)
    float* fbc = (float*)(smem + 16384); // [128][32] f32 (16KB)
    const int a = lane & 3;
#pragma unroll
    for (int mi = 0; mi < 4; ++mi) {
#pragma unroll
        for (int ci = 0; ci < 4; ++ci) {
            float v0 = acc[mi][ci][0], v1 = acc[mi][ci][1];
            float v2 = acc[mi][ci][2], v3 = acc[mi][ci][3];
            bool hi1 = (lane & 2) != 0;
            float s0 = hi1 ? v0 : v2;
            float s1 = hi1 ? v1 : v3;
            float r0 = __shfl_xor(s0, 2, 64);
            float r1 = __shfl_xor(s1, 2, 64);
            if (hi1) { v0 = r0; v1 = r1; } else { v2 = r0; v3 = r1; }
            bool hi0 = (lane & 1) != 0;
            float t0 = hi0 ? v0 : v1;
            float t1 = hi0 ? v2 : v3;
            float q0 = __shfl_xor(t0, 1, 64);
            float q1 = __shfl_xor(t1, 1, 64);
            if (hi0) { v0 = q0; v2 = q1; } else { v1 = q0; v3 = q1; }
            // v0..v3 = pre-bias conv for gates i,f,o,g at (row, h)
            int rl = waveM * 64 + mi * 16 + ((lane >> 4) << 2) + a;
            int hl = waveN * 16 + ci * 4 + ((lane & 15) >> 2);
            int m = m0 + rl;
            int hh = h0 + hl;
            float iv = sigmoidf_(v0 + bias[hh]);
            float fv = sigmoidf_(v1 + bias[512 + hh]);
            float ov = sigmoidf_(v2 + bias[1024 + hh]);
            float gv = tanhf_(v3 + bias[1536 + hh]);
            float cold = (m < MT) ? c_cur[(size_t)m * 512 + hh] : 0.f;
            float cnew = fv * cold + iv * gv;
            float hnew = ov * tanhf_(cnew);
            int fo = rl * 32 + (hl ^ ((rl & 7) << 2));
            fbh[fo] = hnew;
            fbc[fo] = cnew;
        }
    }
    __syncthreads();
#pragma unroll
    for (int q = 0; q < 4; ++q) {
        int cid = q * 256 + tid;
        int row = cid >> 3;
        int c8 = cid & 7;
        int m = m0 + row;
        int fo = row * 32 + ((c8 * 4) ^ ((row & 7) << 2));
        float4 vh = *(const float4*)&fbh[fo];
        float4 vc = *(const float4*)&fbc[fo];
        if (m < MT) {
            *(float4*)&out[(size_t)m * 512 + h0 + c8 * 4] = vh;
            *(float4*)&out[(size_t)10240000 + (size_t)m * 512 + h0 + c8 * 4] = vc;
        }
    }
}

extern "C" void kernel_launch(void* const* d_in, const int* in_sizes, int n_in,
                              void* d_out, int out_size, void* d_ws, size_t ws_size,
                              hipStream_t stream) {
    const float* x    = (const float*)d_in[0];
    const float* h    = (const float*)d_in[1];
    const float* c    = (const float*)d_in[2];
    const int*   ei   = (const int*)d_in[3];
    const float* W    = (const float*)d_in[4];
    const float* bias = (const float*)d_in[5];
    float* out = (float*)d_out;
    (void)in_sizes; (void)n_in; (void)out_size; (void)ws_size;

    const int* src = ei;
    const int* dst = ei + EE;

    char* ws = (char*)d_ws;
    size_t off = 0;
    auto alloc = [&](size_t bytes) -> void* {
        void* p = ws + off;
        off = (off + bytes + 255) & ~(size_t)255;
        return p;
    };
    unsigned short* agg = (unsigned short*)alloc((size_t)MPAD * DD * 2);
    unsigned short* Wt  = (unsigned short*)alloc((size_t)FOURH * DD * 2);
    unsigned short* xhc = (unsigned short*)alloc((size_t)NN * 2048 * 2);
    int*   counts  = (int*)alloc(NN * 4);
    int*   offsets = (int*)alloc((NN + 1) * 4);
    int*   cursor  = (int*)alloc(NN * 4);
    float* dinv    = (float*)alloc(NN * 4);
    float* invdeg  = (float*)alloc(NN * 4);
    int*   csr     = (int*)alloc(EE * 4);
    float* csr_w   = (float*)alloc(EE * 4);

    hipMemsetAsync(counts, 0, NN * 4, stream);
    prep_kernel<<<NN + 2048 + 224 + 625, 256, 0, stream>>>(x, h, W, dst, xhc, Wt, agg, counts);
    scan_kernel<<<1, 1024, 0, stream>>>(counts, offsets, cursor, dinv, invdeg);
    fill_kernel<<<(EE + 255) / 256, 256, 0, stream>>>(src, dst, cursor, dinv, csr, csr_w);
    agg_kernel<<<NN, 256, 0, stream>>>(xhc, csr, csr_w, offsets, invdeg, agg);
    gemm_lstm_kernel<<<2528, 256, 0, stream>>>(agg, Wt, bias, c, out);
}

// Round 13
// 278.414 us; speedup vs baseline: 1.0336x; 1.0336x over previous
//
#include <hip/hip_runtime.h>

#define NN 10000
#define EE 160000
#define DD 1024          // D_IN + H
#define FOURH 2048
#define HH 512
#define MT 20000         // B*N
#define MPAD 20224       // 158 * 128

typedef __attribute__((ext_vector_type(8))) short bf16x8;
typedef __attribute__((ext_vector_type(4))) float f32x4;

typedef __attribute__((address_space(1))) void gvoid;
typedef __attribute__((address_space(3))) void lvoid;

__device__ inline void gload16(const void* g, void* l) {
    __builtin_amdgcn_global_load_lds((gvoid*)g, (lvoid*)l, 16, 0, 0);
}

__device__ inline unsigned short f2bf(float f) {
    unsigned u = __float_as_uint(f);
    u += 0x7fff + ((u >> 16) & 1);   // RNE
    return (unsigned short)(u >> 16);
}

__device__ inline float bflo(unsigned u) { return __uint_as_float(u << 16); }
__device__ inline float bfhi(unsigned u) { return __uint_as_float(u & 0xffff0000u); }

__device__ inline float sigmoidf_(float x) {
    x = fminf(fmaxf(x, -30.f), 30.f);
    return 1.f / (1.f + __expf(-x));
}
__device__ inline float tanhf_(float x) {
    x = fminf(fmaxf(x, -15.f), 15.f);
    float e = __expf(2.f * x);
    return (e - 1.f) / (e + 1.f);
}

// ---------------- CSR build ----------------

// 1-block hierarchical scan: wave shfl-scan + 16-partial scan (3 barriers/chunk)
__global__ __launch_bounds__(1024) void scan_kernel(
    const int* __restrict__ counts, int* __restrict__ offsets,
    int* __restrict__ cursor, float* __restrict__ dinv,
    float* __restrict__ invdeg)
{
    __shared__ int wsum[16];
    int tid = threadIdx.x;
    int lane = tid & 63, wv = tid >> 6;
    if (tid == 0) offsets[0] = 0;
    int running = 0;
    for (int base = 0; base < NN; base += 1024) {
        int i = base + tid;
        int v = (i < NN) ? counts[i] : 0;
        int x = v;
#pragma unroll
        for (int d = 1; d < 64; d <<= 1) {
            int t = __shfl_up(x, d, 64);
            if (lane >= d) x += t;
        }
        if (lane == 63) wsum[wv] = x;
        __syncthreads();
        if (wv == 0) {
            int ws = (lane < 16) ? wsum[lane] : 0;
#pragma unroll
            for (int d = 1; d < 16; d <<= 1) {
                int t = __shfl_up(ws, d, 64);
                if (lane >= d) ws += t;
            }
            if (lane < 16) wsum[lane] = ws;
        }
        __syncthreads();
        int wbase = (wv == 0) ? 0 : wsum[wv - 1];
        int incl = x + wbase + running;
        if (i < NN) {
            offsets[i + 1] = incl;
            cursor[i] = incl - v;            // exclusive
            float deg = (float)(v + 1);
            dinv[i] = rsqrtf(deg);
            invdeg[i] = 1.0f / deg;
        }
        running += wsum[15];
        __syncthreads();
    }
}

__global__ void fill_kernel(const int* __restrict__ src, const int* __restrict__ dst,
                            int* __restrict__ cursor, const float* __restrict__ dinv,
                            int* __restrict__ csr_src, float* __restrict__ csr_w) {
    int e = blockIdx.x * blockDim.x + threadIdx.x;
    if (e < EE) {
        int s = src[e], d = dst[e];
        int p = atomicAdd(&cursor[d], 1);
        csr_src[p] = s;
        csr_w[p] = dinv[s] * dinv[d];
    }
}

// ---------------- fused prep: convert + W-transpose + agg-pad-zero + count ---
// blocks [0,NN): x,h -> packed bf16 rows xhc[n][2048]
// blocks [NN,NN+2048): W[k][j] -> bf16 Wt[j][k]
// blocks [NN+2048,NN+2048+224): zero agg pad rows
// blocks [NN+2048+224, +625): degree count (atomics; overlaps streaming work)

__global__ __launch_bounds__(256) void prep_kernel(
    const float* __restrict__ x, const float* __restrict__ h,
    const float* __restrict__ W, const int* __restrict__ dst,
    unsigned short* __restrict__ xhc, unsigned short* __restrict__ Wt,
    unsigned short* __restrict__ agg, int* __restrict__ counts)
{
    __shared__ float tile[32][33];
    int b = blockIdx.x;
    int t = threadIdx.x;
    if (b < NN) {
        int n = b;
        int sec = t >> 6;        // 0..3
        int li = t & 63;         // 8 floats each
        const float* srcp;
        if (sec == 0)      srcp = x + (size_t)n * 512 + li * 8;
        else if (sec == 1) srcp = h + (size_t)n * 512 + li * 8;
        else if (sec == 2) srcp = x + (size_t)(NN + n) * 512 + li * 8;
        else               srcp = h + (size_t)(NN + n) * 512 + li * 8;
        float4 v0 = *(const float4*)srcp;
        float4 v1 = *(const float4*)(srcp + 4);
        uint4 o;
        o.x = f2bf(v0.x) | ((unsigned)f2bf(v0.y) << 16);
        o.y = f2bf(v0.z) | ((unsigned)f2bf(v0.w) << 16);
        o.z = f2bf(v1.x) | ((unsigned)f2bf(v1.y) << 16);
        o.w = f2bf(v1.z) | ((unsigned)f2bf(v1.w) << 16);
        *(uint4*)(xhc + (size_t)n * 2048 + t * 8) = o;
    } else if (b < NN + 2048) {
        int idx = b - NN;
        int k0 = (idx & 31) * 32;
        int j0 = (idx >> 5) * 32;
        int tx = t & 31;
        int ty = t >> 5;         // 0..7
#pragma unroll
        for (int i = 0; i < 32; i += 8)
            tile[ty + i][tx] = W[(size_t)(k0 + ty + i) * FOURH + (j0 + tx)];
        __syncthreads();
#pragma unroll
        for (int i = 0; i < 32; i += 8)
            Wt[(size_t)(j0 + ty + i) * DD + (k0 + tx)] = f2bf(tile[tx][ty + i]);
    } else if (b < NN + 2048 + 224) {
        int idx = (b - NN - 2048) * 256 + t;       // 224*256 = 57344 ushort4
        ushort4* p = (ushort4*)(agg + (size_t)MT * DD);
        p[idx] = make_ushort4(0, 0, 0, 0);
    } else {
        int e = (b - NN - 2048 - 224) * 256 + t;   // 625*256 = 160000
        if (e < EE) atomicAdd(&counts[dst[e]], 1);
    }
}

// ---------------- aggregation (bf16 gather, fp32 accumulate, 4-edge MLP) -----

__global__ __launch_bounds__(256) void agg_kernel(
    const unsigned short* __restrict__ xhc,
    const int* __restrict__ csr_src, const float* __restrict__ csr_w,
    const int* __restrict__ offsets, const float* __restrict__ invdeg,
    unsigned short* __restrict__ agg)
{
    int n = blockIdx.x;
    int t = threadIdx.x;                 // 8 bf16 per thread of the 2048-wide row
    const unsigned short* base = xhc + t * 8;
    float a0 = 0, a1 = 0, a2 = 0, a3 = 0, a4 = 0, a5 = 0, a6 = 0, a7 = 0;
    int beg = offsets[n], end = offsets[n + 1];
    int e = beg;
    for (; e + 4 <= end; e += 4) {
        int s0 = csr_src[e], s1 = csr_src[e + 1], s2 = csr_src[e + 2], s3 = csr_src[e + 3];
        float w0 = csr_w[e], w1 = csr_w[e + 1], w2 = csr_w[e + 2], w3 = csr_w[e + 3];
        uint4 v0 = *(const uint4*)(base + (size_t)s0 * 2048);
        uint4 v1 = *(const uint4*)(base + (size_t)s1 * 2048);
        uint4 v2 = *(const uint4*)(base + (size_t)s2 * 2048);
        uint4 v3 = *(const uint4*)(base + (size_t)s3 * 2048);
        a0 += w0 * bflo(v0.x); a1 += w0 * bfhi(v0.x);
        a2 += w0 * bflo(v0.y); a3 += w0 * bfhi(v0.y);
        a4 += w0 * bflo(v0.z); a5 += w0 * bfhi(v0.z);
        a6 += w0 * bflo(v0.w); a7 += w0 * bfhi(v0.w);
        a0 += w1 * bflo(v1.x); a1 += w1 * bfhi(v1.x);
        a2 += w1 * bflo(v1.y); a3 += w1 * bfhi(v1.y);
        a4 += w1 * bflo(v1.z); a5 += w1 * bfhi(v1.z);
        a6 += w1 * bflo(v1.w); a7 += w1 * bfhi(v1.w);
        a0 += w2 * bflo(v2.x); a1 += w2 * bfhi(v2.x);
        a2 += w2 * bflo(v2.y); a3 += w2 * bfhi(v2.y);
        a4 += w2 * bflo(v2.z); a5 += w2 * bfhi(v2.z);
        a6 += w2 * bflo(v2.w); a7 += w2 * bfhi(v2.w);
        a0 += w3 * bflo(v3.x); a1 += w3 * bfhi(v3.x);
        a2 += w3 * bflo(v3.y); a3 += w3 * bfhi(v3.y);
        a4 += w3 * bflo(v3.z); a5 += w3 * bfhi(v3.z);
        a6 += w3 * bflo(v3.w); a7 += w3 * bfhi(v3.w);
    }
    for (; e < end; ++e) {
        int s = csr_src[e];
        float w = csr_w[e];
        uint4 v = *(const uint4*)(base + (size_t)s * 2048);
        a0 += w * bflo(v.x); a1 += w * bfhi(v.x);
        a2 += w * bflo(v.y); a3 += w * bfhi(v.y);
        a4 += w * bflo(v.z); a5 += w * bfhi(v.z);
        a6 += w * bflo(v.w); a7 += w * bfhi(v.w);
    }
    float sw = invdeg[n];
    {
        uint4 v = *(const uint4*)(base + (size_t)n * 2048);
        a0 += sw * bflo(v.x); a1 += sw * bfhi(v.x);
        a2 += sw * bflo(v.y); a3 += sw * bfhi(v.y);
        a4 += sw * bflo(v.z); a5 += sw * bfhi(v.z);
        a6 += sw * bflo(v.w); a7 += sw * bfhi(v.w);
    }
    uint4 o;
    o.x = f2bf(a0) | ((unsigned)f2bf(a1) << 16);
    o.y = f2bf(a2) | ((unsigned)f2bf(a3) << 16);
    o.z = f2bf(a4) | ((unsigned)f2bf(a5) << 16);
    o.w = f2bf(a6) | ((unsigned)f2bf(a7) << 16);
    int bsel = t >> 7;                   // batch
    int d = (t & 127) * 8;               // dim within 1024
    *(uint4*)(agg + ((size_t)(bsel * NN + n)) * DD + d) = o;
}

// ---------------- GEMM + fused LSTM epilogue (r11 config: best measured) -----
// Read-economy build on the m97 mechanism: 128x256 tile (cols interleaved:
// gate=c&3, h=h0+(c>>2)), BK=64, 256 thr = 4 waves (2M x 2N), per-wave 64x128,
// acc[4][8]. Single-buffered 48KB LDS, 3 blocks/CU. 2-barrier compiler-scheduled
// loop. Swizzle = r6-measured conflict-free: 128B rows, phys 16B slot s of row r
// holds k-chunk s^(r&7) (pre-swizzled global source, linear LDS dest); frag slot
// ((lane>>4)^(lane&7)), k-half via ^64. Grid 1264 = 8 XCD chunks x 158,
// h-tile-fastest (8 consecutive blocks share one 256KB A-panel).
// NOTE (measured r12): (256,5)+merged-epilogue regresses (VGPR 48 squeeze,
// WRITE 80->98MB from interleaved h/c streams) — keep (256,3) + separate passes.

__global__ __launch_bounds__(256, 3) void gemm_lstm_kernel(
    const unsigned short* __restrict__ agg,
    const unsigned short* __restrict__ Wt,
    const float* __restrict__ bias,
    const float* __restrict__ c_cur,
    float* __restrict__ out)
{
    __shared__ char smem[49152];        // A [128][128B] at 0, B [256][128B] at 16384

    const int tid = threadIdx.x;
    const int lane = tid & 63;
    const int wave = tid >> 6;          // 0..3
    const int waveM = wave >> 1;        // 0..1 (64 rows each)
    const int waveN = wave & 1;         // 0..1 (128 interleaved cols = 32 h each)

    const int orig = blockIdx.x;        // 1264 = 8 * 158
    const int f = (orig & 7) * 158 + (orig >> 3);
    const int blockM = f >> 3;          // 0..157
    const int h0 = (f & 7) * 64;
    const int m0 = blockM * 128;

    // fragment read offsets (kh=0); kh=1 via ^64 (slot s holds chunk s^(r&7))
    const int slot = ((lane >> 4) ^ (lane & 7)) * 16;
    const int aOff = (waveM * 64 + (lane & 15)) * 128 + slot;
    const int bOff = 16384 + (waveN * 128 + (lane & 15)) * 128 + slot;

    // staging: A chunk q=l*256+tid -> row l*32+(tid>>3); B chunk -> col l*32+(tid>>3)
    const int koff = 8 * ((tid & 7) ^ ((tid >> 3) & 7));
    const int u = tid >> 3;
    const unsigned short* aSrc = agg + (size_t)(m0 + u) * DD + koff;
    const unsigned short* bSrc = Wt + (size_t)((u & 3) * 512 + h0 + (u >> 2)) * DD + koff;

    f32x4 acc[4][8];
#pragma unroll
    for (int i = 0; i < 4; ++i)
#pragma unroll
        for (int j = 0; j < 8; ++j) {
            f32x4 z = {0.f, 0.f, 0.f, 0.f};
            acc[i][j] = z;
        }

    for (int kt = 0; kt < 16; ++kt) {
        __syncthreads();
#pragma unroll
        for (int l = 0; l < 4; ++l)
            gload16(aSrc + (size_t)l * 32 * DD + kt * 64, smem + l * 4096 + tid * 16);
#pragma unroll
        for (int l = 0; l < 8; ++l)
            gload16(bSrc + (size_t)l * 8 * DD + kt * 64, smem + 16384 + l * 4096 + tid * 16);
        __syncthreads();
#pragma unroll
        for (int ksub = 0; ksub < 2; ++ksub) {
            const int kx = ksub * 64;
            bf16x8 aF[4];
#pragma unroll
            for (int mi = 0; mi < 4; ++mi)
                aF[mi] = *(const bf16x8*)(smem + (aOff ^ kx) + mi * 2048);
#pragma unroll
            for (int ci = 0; ci < 8; ++ci) {
                bf16x8 bF = *(const bf16x8*)(smem + (bOff ^ kx) + ci * 2048);
#pragma unroll
                for (int mi = 0; mi < 4; ++mi)
                    acc[mi][ci] = __builtin_amdgcn_mfma_f32_16x16x32_bf16(aF[mi], bF, acc[mi][ci], 0, 0, 0);
            }
        }
    }

    // ---- epilogue: quad transpose -> LSTM math -> LDS-staged coalesced stores ----
    __syncthreads();                     // all LDS reads done; reuse smem
    float* fb = (float*)smem;            // [128][64] f32 (32KB), h-XOR ((row&7)<<2)
    const int a = lane & 3;
    float cnewR[4][8];
#pragma unroll
    for (int mi = 0; mi < 4; ++mi) {
#pragma unroll
        for (int ci = 0; ci < 8; ++ci) {
            float v0 = acc[mi][ci][0], v1 = acc[mi][ci][1];
            float v2 = acc[mi][ci][2], v3 = acc[mi][ci][3];
            bool hi1 = (lane & 2) != 0;
            float s0 = hi1 ? v0 : v2;
            float s1 = hi1 ? v1 : v3;
            float r0 = __shfl_xor(s0, 2, 64);
            float r1 = __shfl_xor(s1, 2, 64);
            if (hi1) { v0 = r0; v1 = r1; } else { v2 = r0; v3 = r1; }
            bool hi0 = (lane & 1) != 0;
            float t0 = hi0 ? v0 : v1;
            float t1 = hi0 ? v2 : v3;
            float q0 = __shfl_xor(t0, 1, 64);
            float q1 = __shfl_xor(t1, 1, 64);
            if (hi0) { v0 = q0; v2 = q1; } else { v1 = q0; v3 = q1; }
            // v0..v3 = pre-bias conv for gates i,f,o,g at (row, h)
            int rl = waveM * 64 + mi * 16 + ((lane >> 4) << 2) + a;
            int hl = waveN * 32 + ci * 4 + ((lane & 15) >> 2);
            int m = m0 + rl;
            int hh = h0 + hl;
            float iv = sigmoidf_(v0 + bias[hh]);
            float fv = sigmoidf_(v1 + bias[512 + hh]);
            float ov = sigmoidf_(v2 + bias[1024 + hh]);
            float gv = tanhf_(v3 + bias[1536 + hh]);
            float cold = (m < MT) ? c_cur[(size_t)m * 512 + hh] : 0.f;
            float cnew = fv * cold + iv * gv;
            float hnew = ov * tanhf_(cnew);
            cnewR[mi][ci] = cnew;
            fb[rl * 64 + (hl ^ ((rl & 7) << 2))] = hnew;
        }
    }
    __syncthreads();
#pragma unroll
    for (int q = 0; q < 8; ++q) {
        int cid = q * 256 + tid;
        int row = cid >> 4;
        int c16 = cid & 15;
        int m = m0 + row;
        float4 v = *(const float4*)&fb[row * 64 + ((c16 * 4) ^ ((row & 7) << 2))];
        if (m < MT) *(float4*)&out[(size_t)m * 512 + h0 + c16 * 4] = v;
    }
    __syncthreads();
#pragma unroll
    for (int mi = 0; mi < 4; ++mi)
#pragma unroll
        for (int ci = 0; ci < 8; ++ci) {
            int rl = waveM * 64 + mi * 16 + ((lane >> 4) << 2) + a;
            int hl = waveN * 32 + ci * 4 + ((lane & 15) >> 2);
            fb[rl * 64 + (hl ^ ((rl & 7) << 2))] = cnewR[mi][ci];
        }
    __syncthreads();
#pragma unroll
    for (int q = 0; q < 8; ++q) {
        int cid = q * 256 + tid;
        int row = cid >> 4;
        int c16 = cid & 15;
        int m = m0 + row;
        float4 v = *(const float4*)&fb[row * 64 + ((c16 * 4) ^ ((row & 7) << 2))];
        if (m < MT) *(float4*)&out[(size_t)10240000 + (size_t)m * 512 + h0 + c16 * 4] = v;
    }
}

extern "C" void kernel_launch(void* const* d_in, const int* in_sizes, int n_in,
                              void* d_out, int out_size, void* d_ws, size_t ws_size,
                              hipStream_t stream) {
    const float* x    = (const float*)d_in[0];
    const float* h    = (const float*)d_in[1];
    const float* c    = (const float*)d_in[2];
    const int*   ei   = (const int*)d_in[3];
    const float* W    = (const float*)d_in[4];
    const float* bias = (const float*)d_in[5];
    float* out = (float*)d_out;
    (void)in_sizes; (void)n_in; (void)out_size; (void)ws_size;

    const int* src = ei;
    const int* dst = ei + EE;

    char* ws = (char*)d_ws;
    size_t off = 0;
    auto alloc = [&](size_t bytes) -> void* {
        void* p = ws + off;
        off = (off + bytes + 255) & ~(size_t)255;
        return p;
    };
    unsigned short* agg = (unsigned short*)alloc((size_t)MPAD * DD * 2);
    unsigned short* Wt  = (unsigned short*)alloc((size_t)FOURH * DD * 2);
    unsigned short* xhc = (unsigned short*)alloc((size_t)NN * 2048 * 2);
    int*   counts  = (int*)alloc(NN * 4);
    int*   offsets = (int*)alloc((NN + 1) * 4);
    int*   cursor  = (int*)alloc(NN * 4);
    float* dinv    = (float*)alloc(NN * 4);
    float* invdeg  = (float*)alloc(NN * 4);
    int*   csr     = (int*)alloc(EE * 4);
    float* csr_w   = (float*)alloc(EE * 4);

    hipMemsetAsync(counts, 0, NN * 4, stream);
    prep_kernel<<<NN + 2048 + 224 + 625, 256, 0, stream>>>(x, h, W, dst, xhc, Wt, agg, counts);
    scan_kernel<<<1, 1024, 0, stream>>>(counts, offsets, cursor, dinv, invdeg);
    fill_kernel<<<(EE + 255) / 256, 256, 0, stream>>>(src, dst, cursor, dinv, csr, csr_w);
    agg_kernel<<<NN, 256, 0, stream>>>(xhc, csr, csr_w, offsets, invdeg, agg);
    gemm_lstm_kernel<<<1264, 256, 0, stream>>>(agg, Wt, bias, c, out);
}

// Round 14
// 275.451 us; speedup vs baseline: 1.0448x; 1.0108x over previous
//
#include <hip/hip_runtime.h>

#define NN 10000
#define EE 160000
#define DD 1024          // D_IN + H
#define FOURH 2048
#define HH 512
#define MT 20000         // B*N
#define MPAD 20224       // 158 * 128

typedef __attribute__((ext_vector_type(8))) short bf16x8;
typedef __attribute__((ext_vector_type(4))) float f32x4;

typedef __attribute__((address_space(1))) void gvoid;
typedef __attribute__((address_space(3))) void lvoid;

__device__ inline void gload16(const void* g, void* l) {
    __builtin_amdgcn_global_load_lds((gvoid*)g, (lvoid*)l, 16, 0, 0);
}

__device__ inline unsigned short f2bf(float f) {
    unsigned u = __float_as_uint(f);
    u += 0x7fff + ((u >> 16) & 1);   // RNE
    return (unsigned short)(u >> 16);
}

__device__ inline float bflo(unsigned u) { return __uint_as_float(u << 16); }
__device__ inline float bfhi(unsigned u) { return __uint_as_float(u & 0xffff0000u); }

__device__ inline float sigmoidf_(float x) {
    x = fminf(fmaxf(x, -30.f), 30.f);
    return 1.f / (1.f + __expf(-x));
}
__device__ inline float tanhf_(float x) {
    x = fminf(fmaxf(x, -15.f), 15.f);
    float e = __expf(2.f * x);
    return (e - 1.f) / (e + 1.f);
}

// ---------------- CSR build ----------------

// 1-block hierarchical scan: wave shfl-scan + 16-partial scan (3 barriers/chunk)
__global__ __launch_bounds__(1024) void scan_kernel(
    const int* __restrict__ counts, int* __restrict__ offsets,
    int* __restrict__ cursor, float* __restrict__ dinv,
    float* __restrict__ invdeg)
{
    __shared__ int wsum[16];
    int tid = threadIdx.x;
    int lane = tid & 63, wv = tid >> 6;
    if (tid == 0) offsets[0] = 0;
    int running = 0;
    for (int base = 0; base < NN; base += 1024) {
        int i = base + tid;
        int v = (i < NN) ? counts[i] : 0;
        int x = v;
#pragma unroll
        for (int d = 1; d < 64; d <<= 1) {
            int t = __shfl_up(x, d, 64);
            if (lane >= d) x += t;
        }
        if (lane == 63) wsum[wv] = x;
        __syncthreads();
        if (wv == 0) {
            int ws = (lane < 16) ? wsum[lane] : 0;
#pragma unroll
            for (int d = 1; d < 16; d <<= 1) {
                int t = __shfl_up(ws, d, 64);
                if (lane >= d) ws += t;
            }
            if (lane < 16) wsum[lane] = ws;
        }
        __syncthreads();
        int wbase = (wv == 0) ? 0 : wsum[wv - 1];
        int incl = x + wbase + running;
        if (i < NN) {
            offsets[i + 1] = incl;
            cursor[i] = incl - v;            // exclusive
            float deg = (float)(v + 1);
            dinv[i] = rsqrtf(deg);
            invdeg[i] = 1.0f / deg;
        }
        running += wsum[15];
        __syncthreads();
    }
}

__global__ void fill_kernel(const int* __restrict__ src, const int* __restrict__ dst,
                            int* __restrict__ cursor, const float* __restrict__ dinv,
                            int* __restrict__ csr_src, float* __restrict__ csr_w) {
    int e = blockIdx.x * blockDim.x + threadIdx.x;
    if (e < EE) {
        int s = src[e], d = dst[e];
        int p = atomicAdd(&cursor[d], 1);
        csr_src[p] = s;
        csr_w[p] = dinv[s] * dinv[d];
    }
}

// ---------------- fused prep: convert(+count) + W-transpose + agg-pad-zero ---
// blocks [0,NN): x,h -> packed bf16 rows xhc[n][2048]; ALSO each block counts a
//               16-edge segment of dst (16*10000 = 160000 = EE exactly)
// blocks [NN,NN+2048): W[k][j] -> bf16 Wt[j][k]
// blocks [NN+2048,NN+2048+224): zero agg pad rows

__global__ __launch_bounds__(256) void prep_kernel(
    const float* __restrict__ x, const float* __restrict__ h,
    const float* __restrict__ W, const int* __restrict__ dst,
    unsigned short* __restrict__ xhc, unsigned short* __restrict__ Wt,
    unsigned short* __restrict__ agg, int* __restrict__ counts)
{
    __shared__ float tile[32][33];
    int b = blockIdx.x;
    int t = threadIdx.x;
    if (b < NN) {
        int n = b;
        int sec = t >> 6;        // 0..3
        int li = t & 63;         // 8 floats each
        const float* srcp;
        if (sec == 0)      srcp = x + (size_t)n * 512 + li * 8;
        else if (sec == 1) srcp = h + (size_t)n * 512 + li * 8;
        else if (sec == 2) srcp = x + (size_t)(NN + n) * 512 + li * 8;
        else               srcp = h + (size_t)(NN + n) * 512 + li * 8;
        float4 v0 = *(const float4*)srcp;
        float4 v1 = *(const float4*)(srcp + 4);
        uint4 o;
        o.x = f2bf(v0.x) | ((unsigned)f2bf(v0.y) << 16);
        o.y = f2bf(v0.z) | ((unsigned)f2bf(v0.w) << 16);
        o.z = f2bf(v1.x) | ((unsigned)f2bf(v1.y) << 16);
        o.w = f2bf(v1.z) | ((unsigned)f2bf(v1.w) << 16);
        *(uint4*)(xhc + (size_t)n * 2048 + t * 8) = o;
        if (t < 16) {
            int e = n * 16 + t;              // 16 edges per node-block
            atomicAdd(&counts[dst[e]], 1);
        }
    } else if (b < NN + 2048) {
        int idx = b - NN;
        int k0 = (idx & 31) * 32;
        int j0 = (idx >> 5) * 32;
        int tx = t & 31;
        int ty = t >> 5;         // 0..7
#pragma unroll
        for (int i = 0; i < 32; i += 8)
            tile[ty + i][tx] = W[(size_t)(k0 + ty + i) * FOURH + (j0 + tx)];
        __syncthreads();
#pragma unroll
        for (int i = 0; i < 32; i += 8)
            Wt[(size_t)(j0 + ty + i) * DD + (k0 + tx)] = f2bf(tile[tx][ty + i]);
    } else {
        int idx = (b - NN - 2048) * 256 + t;       // 224*256 = 57344 ushort4
        ushort4* p = (ushort4*)(agg + (size_t)MT * DD);
        p[idx] = make_ushort4(0, 0, 0, 0);
    }
}

// ---------------- aggregation (bf16 gather, fp32 acc, 4-edge MLP) ------------
// grid-stride: 2500 blocks x 4 sequential nodes (averages degree draws ->
// halves straggler spread vs 1 node/block).

__global__ __launch_bounds__(256) void agg_kernel(
    const unsigned short* __restrict__ xhc,
    const int* __restrict__ csr_src, const float* __restrict__ csr_w,
    const int* __restrict__ offsets, const float* __restrict__ invdeg,
    unsigned short* __restrict__ agg)
{
    int t = threadIdx.x;                 // 8 bf16 per thread of the 2048-wide row
    const unsigned short* base = xhc + t * 8;
    int bsel = t >> 7;                   // batch
    int d = (t & 127) * 8;               // dim within 1024
    for (int n = blockIdx.x; n < NN; n += 2500) {
        float a0 = 0, a1 = 0, a2 = 0, a3 = 0, a4 = 0, a5 = 0, a6 = 0, a7 = 0;
        int beg = offsets[n], end = offsets[n + 1];
        int e = beg;
        for (; e + 4 <= end; e += 4) {
            int s0 = csr_src[e], s1 = csr_src[e + 1], s2 = csr_src[e + 2], s3 = csr_src[e + 3];
            float w0 = csr_w[e], w1 = csr_w[e + 1], w2 = csr_w[e + 2], w3 = csr_w[e + 3];
            uint4 v0 = *(const uint4*)(base + (size_t)s0 * 2048);
            uint4 v1 = *(const uint4*)(base + (size_t)s1 * 2048);
            uint4 v2 = *(const uint4*)(base + (size_t)s2 * 2048);
            uint4 v3 = *(const uint4*)(base + (size_t)s3 * 2048);
            a0 += w0 * bflo(v0.x); a1 += w0 * bfhi(v0.x);
            a2 += w0 * bflo(v0.y); a3 += w0 * bfhi(v0.y);
            a4 += w0 * bflo(v0.z); a5 += w0 * bfhi(v0.z);
            a6 += w0 * bflo(v0.w); a7 += w0 * bfhi(v0.w);
            a0 += w1 * bflo(v1.x); a1 += w1 * bfhi(v1.x);
            a2 += w1 * bflo(v1.y); a3 += w1 * bfhi(v1.y);
            a4 += w1 * bflo(v1.z); a5 += w1 * bfhi(v1.z);
            a6 += w1 * bflo(v1.w); a7 += w1 * bfhi(v1.w);
            a0 += w2 * bflo(v2.x); a1 += w2 * bfhi(v2.x);
            a2 += w2 * bflo(v2.y); a3 += w2 * bfhi(v2.y);
            a4 += w2 * bflo(v2.z); a5 += w2 * bfhi(v2.z);
            a6 += w2 * bflo(v2.w); a7 += w2 * bfhi(v2.w);
            a0 += w3 * bflo(v3.x); a1 += w3 * bfhi(v3.x);
            a2 += w3 * bflo(v3.y); a3 += w3 * bfhi(v3.y);
            a4 += w3 * bflo(v3.z); a5 += w3 * bfhi(v3.z);
            a6 += w3 * bflo(v3.w); a7 += w3 * bfhi(v3.w);
        }
        for (; e < end; ++e) {
            int s = csr_src[e];
            float w = csr_w[e];
            uint4 v = *(const uint4*)(base + (size_t)s * 2048);
            a0 += w * bflo(v.x); a1 += w * bfhi(v.x);
            a2 += w * bflo(v.y); a3 += w * bfhi(v.y);
            a4 += w * bflo(v.z); a5 += w * bfhi(v.z);
            a6 += w * bflo(v.w); a7 += w * bfhi(v.w);
        }
        float sw = invdeg[n];
        {
            uint4 v = *(const uint4*)(base + (size_t)n * 2048);
            a0 += sw * bflo(v.x); a1 += sw * bfhi(v.x);
            a2 += sw * bflo(v.y); a3 += sw * bfhi(v.y);
            a4 += sw * bflo(v.z); a5 += sw * bfhi(v.z);
            a6 += sw * bflo(v.w); a7 += sw * bfhi(v.w);
        }
        uint4 o;
        o.x = f2bf(a0) | ((unsigned)f2bf(a1) << 16);
        o.y = f2bf(a2) | ((unsigned)f2bf(a3) << 16);
        o.z = f2bf(a4) | ((unsigned)f2bf(a5) << 16);
        o.w = f2bf(a6) | ((unsigned)f2bf(a7) << 16);
        *(uint4*)(agg + ((size_t)(bsel * NN + n)) * DD + d) = o;
    }
}

// ---------------- GEMM + fused LSTM epilogue (r11/r13 config: best measured) --
// Read-economy build on the m97 mechanism: 128x256 tile (cols interleaved:
// gate=c&3, h=h0+(c>>2)), BK=64, 256 thr = 4 waves (2M x 2N), per-wave 64x128,
// acc[4][8]. Single-buffered 48KB LDS, 3 blocks/CU. 2-barrier compiler-scheduled
// loop. Swizzle = r6-measured conflict-free: 128B rows, phys 16B slot s of row r
// holds k-chunk s^(r&7) (pre-swizzled global source, linear LDS dest); frag slot
// ((lane>>4)^(lane&7)), k-half via ^64. Grid 1264 = 8 XCD chunks x 158,
// h-tile-fastest (8 consecutive blocks share one 256KB A-panel).
// Measured plateau 123.6±1 us across 128x128@4blk / 128x256@3blk; (256,5) and
// all single-block deep pipelines regress (r4-r7, r9, r12).

__global__ __launch_bounds__(256, 3) void gemm_lstm_kernel(
    const unsigned short* __restrict__ agg,
    const unsigned short* __restrict__ Wt,
    const float* __restrict__ bias,
    const float* __restrict__ c_cur,
    float* __restrict__ out)
{
    __shared__ char smem[49152];        // A [128][128B] at 0, B [256][128B] at 16384

    const int tid = threadIdx.x;
    const int lane = tid & 63;
    const int wave = tid >> 6;          // 0..3
    const int waveM = wave >> 1;        // 0..1 (64 rows each)
    const int waveN = wave & 1;         // 0..1 (128 interleaved cols = 32 h each)

    const int orig = blockIdx.x;        // 1264 = 8 * 158
    const int f = (orig & 7) * 158 + (orig >> 3);
    const int blockM = f >> 3;          // 0..157
    const int h0 = (f & 7) * 64;
    const int m0 = blockM * 128;

    // fragment read offsets (kh=0); kh=1 via ^64 (slot s holds chunk s^(r&7))
    const int slot = ((lane >> 4) ^ (lane & 7)) * 16;
    const int aOff = (waveM * 64 + (lane & 15)) * 128 + slot;
    const int bOff = 16384 + (waveN * 128 + (lane & 15)) * 128 + slot;

    // staging: A chunk q=l*256+tid -> row l*32+(tid>>3); B chunk -> col l*32+(tid>>3)
    const int koff = 8 * ((tid & 7) ^ ((tid >> 3) & 7));
    const int u = tid >> 3;
    const unsigned short* aSrc = agg + (size_t)(m0 + u) * DD + koff;
    const unsigned short* bSrc = Wt + (size_t)((u & 3) * 512 + h0 + (u >> 2)) * DD + koff;

    f32x4 acc[4][8];
#pragma unroll
    for (int i = 0; i < 4; ++i)
#pragma unroll
        for (int j = 0; j < 8; ++j) {
            f32x4 z = {0.f, 0.f, 0.f, 0.f};
            acc[i][j] = z;
        }

    for (int kt = 0; kt < 16; ++kt) {
        __syncthreads();
#pragma unroll
        for (int l = 0; l < 4; ++l)
            gload16(aSrc + (size_t)l * 32 * DD + kt * 64, smem + l * 4096 + tid * 16);
#pragma unroll
        for (int l = 0; l < 8; ++l)
            gload16(bSrc + (size_t)l * 8 * DD + kt * 64, smem + 16384 + l * 4096 + tid * 16);
        __syncthreads();
#pragma unroll
        for (int ksub = 0; ksub < 2; ++ksub) {
            const int kx = ksub * 64;
            bf16x8 aF[4];
#pragma unroll
            for (int mi = 0; mi < 4; ++mi)
                aF[mi] = *(const bf16x8*)(smem + (aOff ^ kx) + mi * 2048);
#pragma unroll
            for (int ci = 0; ci < 8; ++ci) {
                bf16x8 bF = *(const bf16x8*)(smem + (bOff ^ kx) + ci * 2048);
#pragma unroll
                for (int mi = 0; mi < 4; ++mi)
                    acc[mi][ci] = __builtin_amdgcn_mfma_f32_16x16x32_bf16(aF[mi], bF, acc[mi][ci], 0, 0, 0);
            }
        }
    }

    // ---- epilogue: quad transpose -> LSTM math -> LDS-staged coalesced stores ----
    __syncthreads();                     // all LDS reads done; reuse smem
    float* fb = (float*)smem;            // [128][64] f32 (32KB), h-XOR ((row&7)<<2)
    const int a = lane & 3;
    float cnewR[4][8];
#pragma unroll
    for (int mi = 0; mi < 4; ++mi) {
#pragma unroll
        for (int ci = 0; ci < 8; ++ci) {
            float v0 = acc[mi][ci][0], v1 = acc[mi][ci][1];
            float v2 = acc[mi][ci][2], v3 = acc[mi][ci][3];
            bool hi1 = (lane & 2) != 0;
            float s0 = hi1 ? v0 : v2;
            float s1 = hi1 ? v1 : v3;
            float r0 = __shfl_xor(s0, 2, 64);
            float r1 = __shfl_xor(s1, 2, 64);
            if (hi1) { v0 = r0; v1 = r1; } else { v2 = r0; v3 = r1; }
            bool hi0 = (lane & 1) != 0;
            float t0 = hi0 ? v0 : v1;
            float t1 = hi0 ? v2 : v3;
            float q0 = __shfl_xor(t0, 1, 64);
            float q1 = __shfl_xor(t1, 1, 64);
            if (hi0) { v0 = q0; v2 = q1; } else { v1 = q0; v3 = q1; }
            // v0..v3 = pre-bias conv for gates i,f,o,g at (row, h)
            int rl = waveM * 64 + mi * 16 + ((lane >> 4) << 2) + a;
            int hl = waveN * 32 + ci * 4 + ((lane & 15) >> 2);
            int m = m0 + rl;
            int hh = h0 + hl;
            float iv = sigmoidf_(v0 + bias[hh]);
            float fv = sigmoidf_(v1 + bias[512 + hh]);
            float ov = sigmoidf_(v2 + bias[1024 + hh]);
            float gv = tanhf_(v3 + bias[1536 + hh]);
            float cold = (m < MT) ? c_cur[(size_t)m * 512 + hh] : 0.f;
            float cnew = fv * cold + iv * gv;
            float hnew = ov * tanhf_(cnew);
            cnewR[mi][ci] = cnew;
            fb[rl * 64 + (hl ^ ((rl & 7) << 2))] = hnew;
        }
    }
    __syncthreads();
#pragma unroll
    for (int q = 0; q < 8; ++q) {
        int cid = q * 256 + tid;
        int row = cid >> 4;
        int c16 = cid & 15;
        int m = m0 + row;
        float4 v = *(const float4*)&fb[row * 64 + ((c16 * 4) ^ ((row & 7) << 2))];
        if (m < MT) *(float4*)&out[(size_t)m * 512 + h0 + c16 * 4] = v;
    }
    __syncthreads();
#pragma unroll
    for (int mi = 0; mi < 4; ++mi)
#pragma unroll
        for (int ci = 0; ci < 8; ++ci) {
            int rl = waveM * 64 + mi * 16 + ((lane >> 4) << 2) + a;
            int hl = waveN * 32 + ci * 4 + ((lane & 15) >> 2);
            fb[rl * 64 + (hl ^ ((rl & 7) << 2))] = cnewR[mi][ci];
        }
    __syncthreads();
#pragma unroll
    for (int q = 0; q < 8; ++q) {
        int cid = q * 256 + tid;
        int row = cid >> 4;
        int c16 = cid & 15;
        int m = m0 + row;
        float4 v = *(const float4*)&fb[row * 64 + ((c16 * 4) ^ ((row & 7) << 2))];
        if (m < MT) *(float4*)&out[(size_t)10240000 + (size_t)m * 512 + h0 + c16 * 4] = v;
    }
}

extern "C" void kernel_launch(void* const* d_in, const int* in_sizes, int n_in,
                              void* d_out, int out_size, void* d_ws, size_t ws_size,
                              hipStream_t stream) {
    const float* x    = (const float*)d_in[0];
    const float* h    = (const float*)d_in[1];
    const float* c    = (const float*)d_in[2];
    const int*   ei   = (const int*)d_in[3];
    const float* W    = (const float*)d_in[4];
    const float* bias = (const float*)d_in[5];
    float* out = (float*)d_out;
    (void)in_sizes; (void)n_in; (void)out_size; (void)ws_size;

    const int* src = ei;
    const int* dst = ei + EE;

    char* ws = (char*)d_ws;
    size_t off = 0;
    auto alloc = [&](size_t bytes) -> void* {
        void* p = ws + off;
        off = (off + bytes + 255) & ~(size_t)255;
        return p;
    };
    unsigned short* agg = (unsigned short*)alloc((size_t)MPAD * DD * 2);
    unsigned short* Wt  = (unsigned short*)alloc((size_t)FOURH * DD * 2);
    unsigned short* xhc = (unsigned short*)alloc((size_t)NN * 2048 * 2);
    int*   counts  = (int*)alloc(NN * 4);
    int*   offsets = (int*)alloc((NN + 1) * 4);
    int*   cursor  = (int*)alloc(NN * 4);
    float* dinv    = (float*)alloc(NN * 4);
    float* invdeg  = (float*)alloc(NN * 4);
    int*   csr     = (int*)alloc(EE * 4);
    float* csr_w   = (float*)alloc(EE * 4);

    hipMemsetAsync(counts, 0, NN * 4, stream);
    prep_kernel<<<NN + 2048 + 224, 256, 0, stream>>>(x, h, W, dst, xhc, Wt, agg, counts);
    scan_kernel<<<1, 1024, 0, stream>>>(counts, offsets, cursor, dinv, invdeg);
    fill_kernel<<<(EE + 255) / 256, 256, 0, stream>>>(src, dst, cursor, dinv, csr, csr_w);
    agg_kernel<<<2500, 256, 0, stream>>>(xhc, csr, csr_w, offsets, invdeg, agg);
    gemm_lstm_kernel<<<1264, 256, 0, stream>>>(agg, Wt, bias, c, out);
}

// Round 15
// 222.559 us; speedup vs baseline: 1.2930x; 1.2377x over previous
//
#include <hip/hip_runtime.h>

#define NN 10000
#define EE 160000
#define DD 1024          // D_IN + H
#define FOURH 2048
#define HH 512
#define MT 20000         // B*N
#define MPAD 20224       // 158 * 128

typedef __attribute__((ext_vector_type(8))) short bf16x8;
typedef __attribute__((ext_vector_type(4))) float f32x4;
typedef __attribute__((ext_vector_type(2))) float f32x2;

typedef __attribute__((address_space(1))) void gvoid;
typedef __attribute__((address_space(3))) void lvoid;

__device__ inline void gload16(const void* g, void* l) {
    __builtin_amdgcn_global_load_lds((gvoid*)g, (lvoid*)l, 16, 0, 0);
}

__device__ inline unsigned short f2bf(float f) {
    unsigned u = __float_as_uint(f);
    u += 0x7fff + ((u >> 16) & 1);   // RNE
    return (unsigned short)(u >> 16);
}

__device__ inline float sigmoidf_(float x) {
    x = fminf(fmaxf(x, -30.f), 30.f);
    return 1.f / (1.f + __expf(-x));
}
__device__ inline float tanhf_(float x) {
    x = fminf(fmaxf(x, -15.f), 15.f);
    float e = __expf(2.f * x);
    return (e - 1.f) / (e + 1.f);
}

// ---------------- CSR build ----------------

// 1-block hierarchical scan: wave shfl-scan + 16-partial scan (3 barriers/chunk)
__global__ __launch_bounds__(1024) void scan_kernel(
    const int* __restrict__ counts, int* __restrict__ offsets,
    int* __restrict__ cursor, float* __restrict__ dinv,
    float* __restrict__ invdeg)
{
    __shared__ int wsum[16];
    int tid = threadIdx.x;
    int lane = tid & 63, wv = tid >> 6;
    if (tid == 0) offsets[0] = 0;
    int running = 0;
    for (int base = 0; base < NN; base += 1024) {
        int i = base + tid;
        int v = (i < NN) ? counts[i] : 0;
        int x = v;
#pragma unroll
        for (int d = 1; d < 64; d <<= 1) {
            int t = __shfl_up(x, d, 64);
            if (lane >= d) x += t;
        }
        if (lane == 63) wsum[wv] = x;
        __syncthreads();
        if (wv == 0) {
            int ws = (lane < 16) ? wsum[lane] : 0;
#pragma unroll
            for (int d = 1; d < 16; d <<= 1) {
                int t = __shfl_up(ws, d, 64);
                if (lane >= d) ws += t;
            }
            if (lane < 16) wsum[lane] = ws;
        }
        __syncthreads();
        int wbase = (wv == 0) ? 0 : wsum[wv - 1];
        int incl = x + wbase + running;
        if (i < NN) {
            offsets[i + 1] = incl;
            cursor[i] = incl - v;            // exclusive
            float deg = (float)(v + 1);
            dinv[i] = rsqrtf(deg);
            invdeg[i] = 1.0f / deg;
        }
        running += wsum[15];
        __syncthreads();
    }
}

__global__ void fill_kernel(const int* __restrict__ src, const int* __restrict__ dst,
                            int* __restrict__ cursor, const float* __restrict__ dinv,
                            int* __restrict__ csr_src, float* __restrict__ csr_w) {
    int e = blockIdx.x * blockDim.x + threadIdx.x;
    if (e < EE) {
        int s = src[e], d = dst[e];
        int p = atomicAdd(&cursor[d], 1);
        csr_src[p] = s;
        csr_w[p] = dinv[s] * dinv[d];
    }
}

// ---------------- fused prep: convert(+count) + W-transpose + agg-pad-zero ---
// blocks [0,NN): x,h -> packed fp8(e4m3, HW cvt) rows xhc8[n][2048] (2KB/row);
//               ALSO each block counts a 16-edge segment of dst (16*10000 = EE)
// blocks [NN,NN+2048): W[k][j] -> bf16 Wt[j][k]
// blocks [NN+2048,NN+2048+224): zero agg pad rows

__global__ __launch_bounds__(256) void prep_kernel(
    const float* __restrict__ x, const float* __restrict__ h,
    const float* __restrict__ W, const int* __restrict__ dst,
    unsigned char* __restrict__ xhc8, unsigned short* __restrict__ Wt,
    unsigned short* __restrict__ agg, int* __restrict__ counts)
{
    __shared__ float tile[32][33];
    int b = blockIdx.x;
    int t = threadIdx.x;
    if (b < NN) {
        int n = b;
        int sec = t >> 6;        // 0..3
        int li = t & 63;         // 8 floats each
        const float* srcp;
        if (sec == 0)      srcp = x + (size_t)n * 512 + li * 8;
        else if (sec == 1) srcp = h + (size_t)n * 512 + li * 8;
        else if (sec == 2) srcp = x + (size_t)(NN + n) * 512 + li * 8;
        else               srcp = h + (size_t)(NN + n) * 512 + li * 8;
        float4 v0 = *(const float4*)srcp;
        float4 v1 = *(const float4*)(srcp + 4);
        int lo = __builtin_amdgcn_cvt_pk_fp8_f32(v0.x, v0.y, 0, false);
        lo = __builtin_amdgcn_cvt_pk_fp8_f32(v0.z, v0.w, lo, true);
        int hi = __builtin_amdgcn_cvt_pk_fp8_f32(v1.x, v1.y, 0, false);
        hi = __builtin_amdgcn_cvt_pk_fp8_f32(v1.z, v1.w, hi, true);
        uint2 o8;
        o8.x = (unsigned)lo;
        o8.y = (unsigned)hi;
        *(uint2*)(xhc8 + (size_t)n * 2048 + t * 8) = o8;
        if (t < 16) {
            int e = n * 16 + t;              // 16 edges per node-block
            atomicAdd(&counts[dst[e]], 1);
        }
    } else if (b < NN + 2048) {
        int idx = b - NN;
        int k0 = (idx & 31) * 32;
        int j0 = (idx >> 5) * 32;
        int tx = t & 31;
        int ty = t >> 5;         // 0..7
#pragma unroll
        for (int i = 0; i < 32; i += 8)
            tile[ty + i][tx] = W[(size_t)(k0 + ty + i) * FOURH + (j0 + tx)];
        __syncthreads();
#pragma unroll
        for (int i = 0; i < 32; i += 8)
            Wt[(size_t)(j0 + ty + i) * DD + (k0 + tx)] = f2bf(tile[tx][ty + i]);
    } else {
        int idx = (b - NN - 2048) * 256 + t;       // 224*256 = 57344 ushort4
        ushort4* p = (ushort4*)(agg + (size_t)MT * DD);
        p[idx] = make_ushort4(0, 0, 0, 0);
    }
}

// ---------------- aggregation (fp8 gather, fp32 acc, 4-edge MLP) -------------
// grid-stride: 2500 blocks x 4 sequential nodes. Gather traffic halved vs bf16
// (327MB logical, 20.5MB working set); accumulate fp32; agg output stays bf16.

#define DEC8(V, W8) do { \
    f32x2 p0 = __builtin_amdgcn_cvt_pk_f32_fp8((int)(V).x, false); \
    f32x2 p1 = __builtin_amdgcn_cvt_pk_f32_fp8((int)(V).x, true); \
    f32x2 p2 = __builtin_amdgcn_cvt_pk_f32_fp8((int)(V).y, false); \
    f32x2 p3 = __builtin_amdgcn_cvt_pk_f32_fp8((int)(V).y, true); \
    a0 += (W8) * p0.x; a1 += (W8) * p0.y; \
    a2 += (W8) * p1.x; a3 += (W8) * p1.y; \
    a4 += (W8) * p2.x; a5 += (W8) * p2.y; \
    a6 += (W8) * p3.x; a7 += (W8) * p3.y; \
} while (0)

__global__ __launch_bounds__(256) void agg_kernel(
    const unsigned char* __restrict__ xhc8,
    const int* __restrict__ csr_src, const float* __restrict__ csr_w,
    const int* __restrict__ offsets, const float* __restrict__ invdeg,
    unsigned short* __restrict__ agg)
{
    int t = threadIdx.x;                 // 8 fp8 per thread of the 2048-wide row
    const unsigned char* base = xhc8 + t * 8;
    int bsel = t >> 7;                   // batch
    int d = (t & 127) * 8;               // dim within 1024
    for (int n = blockIdx.x; n < NN; n += 2500) {
        float a0 = 0, a1 = 0, a2 = 0, a3 = 0, a4 = 0, a5 = 0, a6 = 0, a7 = 0;
        int beg = offsets[n], end = offsets[n + 1];
        int e = beg;
        for (; e + 4 <= end; e += 4) {
            int s0 = csr_src[e], s1 = csr_src[e + 1], s2 = csr_src[e + 2], s3 = csr_src[e + 3];
            float w0 = csr_w[e], w1 = csr_w[e + 1], w2 = csr_w[e + 2], w3 = csr_w[e + 3];
            uint2 v0 = *(const uint2*)(base + (size_t)s0 * 2048);
            uint2 v1 = *(const uint2*)(base + (size_t)s1 * 2048);
            uint2 v2 = *(const uint2*)(base + (size_t)s2 * 2048);
            uint2 v3 = *(const uint2*)(base + (size_t)s3 * 2048);
            DEC8(v0, w0);
            DEC8(v1, w1);
            DEC8(v2, w2);
            DEC8(v3, w3);
        }
        for (; e < end; ++e) {
            int s = csr_src[e];
            float w = csr_w[e];
            uint2 v = *(const uint2*)(base + (size_t)s * 2048);
            DEC8(v, w);
        }
        float sw = invdeg[n];
        {
            uint2 v = *(const uint2*)(base + (size_t)n * 2048);
            DEC8(v, sw);
        }
        uint4 o;
        o.x = f2bf(a0) | ((unsigned)f2bf(a1) << 16);
        o.y = f2bf(a2) | ((unsigned)f2bf(a3) << 16);
        o.z = f2bf(a4) | ((unsigned)f2bf(a5) << 16);
        o.w = f2bf(a6) | ((unsigned)f2bf(a7) << 16);
        *(uint4*)(agg + ((size_t)(bsel * NN + n)) * DD + d) = o;
    }
}

// ---------------- GEMM + fused LSTM epilogue (r11/r13 config: best measured) --
// Read-economy build on the m97 mechanism: 128x256 tile (cols interleaved:
// gate=c&3, h=h0+(c>>2)), BK=64, 256 thr = 4 waves (2M x 2N), per-wave 64x128,
// acc[4][8]. Single-buffered 48KB LDS, 3 blocks/CU. 2-barrier compiler-scheduled
// loop. Swizzle = r6-measured conflict-free: 128B rows, phys 16B slot s of row r
// holds k-chunk s^(r&7) (pre-swizzled global source, linear LDS dest); frag slot
// ((lane>>4)^(lane&7)), k-half via ^64. Grid 1264 = 8 XCD chunks x 158,
// h-tile-fastest (8 consecutive blocks share one 256KB A-panel).
// Measured plateau 123.6±1 us across 128x128@4blk / 128x256@3blk; (256,5) and
// all single-block deep pipelines regress (r4-r7, r9, r12).

__global__ __launch_bounds__(256, 3) void gemm_lstm_kernel(
    const unsigned short* __restrict__ agg,
    const unsigned short* __restrict__ Wt,
    const float* __restrict__ bias,
    const float* __restrict__ c_cur,
    float* __restrict__ out)
{
    __shared__ char smem[49152];        // A [128][128B] at 0, B [256][128B] at 16384

    const int tid = threadIdx.x;
    const int lane = tid & 63;
    const int wave = tid >> 6;          // 0..3
    const int waveM = wave >> 1;        // 0..1 (64 rows each)
    const int waveN = wave & 1;         // 0..1 (128 interleaved cols = 32 h each)

    const int orig = blockIdx.x;        // 1264 = 8 * 158
    const int f = (orig & 7) * 158 + (orig >> 3);
    const int blockM = f >> 3;          // 0..157
    const int h0 = (f & 7) * 64;
    const int m0 = blockM * 128;

    // fragment read offsets (kh=0); kh=1 via ^64 (slot s holds chunk s^(r&7))
    const int slot = ((lane >> 4) ^ (lane & 7)) * 16;
    const int aOff = (waveM * 64 + (lane & 15)) * 128 + slot;
    const int bOff = 16384 + (waveN * 128 + (lane & 15)) * 128 + slot;

    // staging: A chunk q=l*256+tid -> row l*32+(tid>>3); B chunk -> col l*32+(tid>>3)
    const int koff = 8 * ((tid & 7) ^ ((tid >> 3) & 7));
    const int u = tid >> 3;
    const unsigned short* aSrc = agg + (size_t)(m0 + u) * DD + koff;
    const unsigned short* bSrc = Wt + (size_t)((u & 3) * 512 + h0 + (u >> 2)) * DD + koff;

    f32x4 acc[4][8];
#pragma unroll
    for (int i = 0; i < 4; ++i)
#pragma unroll
        for (int j = 0; j < 8; ++j) {
            f32x4 z = {0.f, 0.f, 0.f, 0.f};
            acc[i][j] = z;
        }

    for (int kt = 0; kt < 16; ++kt) {
        __syncthreads();
#pragma unroll
        for (int l = 0; l < 4; ++l)
            gload16(aSrc + (size_t)l * 32 * DD + kt * 64, smem + l * 4096 + tid * 16);
#pragma unroll
        for (int l = 0; l < 8; ++l)
            gload16(bSrc + (size_t)l * 8 * DD + kt * 64, smem + 16384 + l * 4096 + tid * 16);
        __syncthreads();
#pragma unroll
        for (int ksub = 0; ksub < 2; ++ksub) {
            const int kx = ksub * 64;
            bf16x8 aF[4];
#pragma unroll
            for (int mi = 0; mi < 4; ++mi)
                aF[mi] = *(const bf16x8*)(smem + (aOff ^ kx) + mi * 2048);
#pragma unroll
            for (int ci = 0; ci < 8; ++ci) {
                bf16x8 bF = *(const bf16x8*)(smem + (bOff ^ kx) + ci * 2048);
#pragma unroll
                for (int mi = 0; mi < 4; ++mi)
                    acc[mi][ci] = __builtin_amdgcn_mfma_f32_16x16x32_bf16(aF[mi], bF, acc[mi][ci], 0, 0, 0);
            }
        }
    }

    // ---- epilogue: quad transpose -> LSTM math -> LDS-staged coalesced stores ----
    __syncthreads();                     // all LDS reads done; reuse smem
    float* fb = (float*)smem;            // [128][64] f32 (32KB), h-XOR ((row&7)<<2)
    const int a = lane & 3;
    float cnewR[4][8];
#pragma unroll
    for (int mi = 0; mi < 4; ++mi) {
#pragma unroll
        for (int ci = 0; ci < 8; ++ci) {
            float v0 = acc[mi][ci][0], v1 = acc[mi][ci][1];
            float v2 = acc[mi][ci][2], v3 = acc[mi][ci][3];
            bool hi1 = (lane & 2) != 0;
            float s0 = hi1 ? v0 : v2;
            float s1 = hi1 ? v1 : v3;
            float r0 = __shfl_xor(s0, 2, 64);
            float r1 = __shfl_xor(s1, 2, 64);
            if (hi1) { v0 = r0; v1 = r1; } else { v2 = r0; v3 = r1; }
            bool hi0 = (lane & 1) != 0;
            float t0 = hi0 ? v0 : v1;
            float t1 = hi0 ? v2 : v3;
            float q0 = __shfl_xor(t0, 1, 64);
            float q1 = __shfl_xor(t1, 1, 64);
            if (hi0) { v0 = q0; v2 = q1; } else { v1 = q0; v3 = q1; }
            // v0..v3 = pre-bias conv for gates i,f,o,g at (row, h)
            int rl = waveM * 64 + mi * 16 + ((lane >> 4) << 2) + a;
            int hl = waveN * 32 + ci * 4 + ((lane & 15) >> 2);
            int m = m0 + rl;
            int hh = h0 + hl;
            float iv = sigmoidf_(v0 + bias[hh]);
            float fv = sigmoidf_(v1 + bias[512 + hh]);
            float ov = sigmoidf_(v2 + bias[1024 + hh]);
            float gv = tanhf_(v3 + bias[1536 + hh]);
            float cold = (m < MT) ? c_cur[(size_t)m * 512 + hh] : 0.f;
            float cnew = fv * cold + iv * gv;
            float hnew = ov * tanhf_(cnew);
            cnewR[mi][ci] = cnew;
            fb[rl * 64 + (hl ^ ((rl & 7) << 2))] = hnew;
        }
    }
    __syncthreads();
#pragma unroll
    for (int q = 0; q < 8; ++q) {
        int cid = q * 256 + tid;
        int row = cid >> 4;
        int c16 = cid & 15;
        int m = m0 + row;
        float4 v = *(const float4*)&fb[row * 64 + ((c16 * 4) ^ ((row & 7) << 2))];
        if (m < MT) *(float4*)&out[(size_t)m * 512 + h0 + c16 * 4] = v;
    }
    __syncthreads();
#pragma unroll
    for (int mi = 0; mi < 4; ++mi)
#pragma unroll
        for (int ci = 0; ci < 8; ++ci) {
            int rl = waveM * 64 + mi * 16 + ((lane >> 4) << 2) + a;
            int hl = waveN * 32 + ci * 4 + ((lane & 15) >> 2);
            fb[rl * 64 + (hl ^ ((rl & 7) << 2))] = cnewR[mi][ci];
        }
    __syncthreads();
#pragma unroll
    for (int q = 0; q < 8; ++q) {
        int cid = q * 256 + tid;
        int row = cid >> 4;
        int c16 = cid & 15;
        int m = m0 + row;
        float4 v = *(const float4*)&fb[row * 64 + ((c16 * 4) ^ ((row & 7) << 2))];
        if (m < MT) *(float4*)&out[(size_t)10240000 + (size_t)m * 512 + h0 + c16 * 4] = v;
    }
}

extern "C" void kernel_launch(void* const* d_in, const int* in_sizes, int n_in,
                              void* d_out, int out_size, void* d_ws, size_t ws_size,
                              hipStream_t stream) {
    const float* x    = (const float*)d_in[0];
    const float* h    = (const float*)d_in[1];
    const float* c    = (const float*)d_in[2];
    const int*   ei   = (const int*)d_in[3];
    const float* W    = (const float*)d_in[4];
    const float* bias = (const float*)d_in[5];
    float* out = (float*)d_out;
    (void)in_sizes; (void)n_in; (void)out_size; (void)ws_size;

    const int* src = ei;
    const int* dst = ei + EE;

    char* ws = (char*)d_ws;
    size_t off = 0;
    auto alloc = [&](size_t bytes) -> void* {
        void* p = ws + off;
        off = (off + bytes + 255) & ~(size_t)255;
        return p;
    };
    unsigned short* agg  = (unsigned short*)alloc((size_t)MPAD * DD * 2);
    unsigned short* Wt   = (unsigned short*)alloc((size_t)FOURH * DD * 2);
    unsigned char*  xhc8 = (unsigned char*)alloc((size_t)NN * 2048);
    int*   counts  = (int*)alloc(NN * 4);
    int*   offsets = (int*)alloc((NN + 1) * 4);
    int*   cursor  = (int*)alloc(NN * 4);
    float* dinv    = (float*)alloc(NN * 4);
    float* invdeg  = (float*)alloc(NN * 4);
    int*   csr     = (int*)alloc(EE * 4);
    float* csr_w   = (float*)alloc(EE * 4);

    hipMemsetAsync(counts, 0, NN * 4, stream);
    prep_kernel<<<NN + 2048 + 224, 256, 0, stream>>>(x, h, W, dst, xhc8, Wt, agg, counts);
    scan_kernel<<<1, 1024, 0, stream>>>(counts, offsets, cursor, dinv, invdeg);
    fill_kernel<<<(EE + 255) / 256, 256, 0, stream>>>(src, dst, cursor, dinv, csr, csr_w);
    agg_kernel<<<2500, 256, 0, stream>>>(xhc8, csr, csr_w, offsets, invdeg, agg);
    gemm_lstm_kernel<<<1264, 256, 0, stream>>>(agg, Wt, bias, c, out);
}